// Round 1
// baseline (363.418 us; speedup 1.0000x reference)
//
#include <hip/hip_runtime.h>
#include <hip/hip_bf16.h>

typedef unsigned short u16;
typedef short s16x8 __attribute__((ext_vector_type(8)));
typedef u16 u16x8 __attribute__((ext_vector_type(8)));
typedef unsigned int u32x4 __attribute__((ext_vector_type(4)));
typedef float f32x4 __attribute__((ext_vector_type(4)));

struct cplx { float x, y; };

#define L_SEQ 2048
#define HID 512
#define NST 64

// ---------------- device scratch (statics; fully rewritten every call) ----------------
__device__ __align__(16) cplx g_A0[NST * NST];
__device__ __align__(16) cplx g_A1[NST * NST];
__device__ __align__(16) cplx g_S[7][NST * NST];  // S[j] = Ab^(2^j), S[6] = Ab^64
__device__ __align__(16) cplx g_Bb[NST];
__device__ __align__(16) cplx g_c[NST];           // conj(C)
__device__ __align__(16) float g_k[L_SEQ];
__device__ __align__(16) u16 g_T[L_SEQ * L_SEQ];  // bf16 Toeplitz, row-major [i][j] = k[i-j]
__device__ __align__(16) u16 g_Xt[HID * L_SEQ];   // bf16 X^T  [h][l]
__device__ __align__(16) u16 g_W1[HID * HID];     // bf16 [n][k]
__device__ __align__(16) u16 g_W2[HID * HID];
__device__ __align__(16) u16 g_H[L_SEQ * HID];    // bf16 gelu(conv out) [l][h]

__device__ __forceinline__ cplx cmul(cplx a, cplx b) {
    return { a.x * b.x - a.y * b.y, a.x * b.y + a.y * b.x };
}
__device__ __forceinline__ cplx cmadd(cplx s, cplx a, cplx b) {
    s.x += a.x * b.x - a.y * b.y;
    s.y += a.x * b.y + a.y * b.x;
    return s;
}
__device__ __forceinline__ u16 f2bf(float f) {
    __hip_bfloat16 h = __float2bfloat16(f);
    union { __hip_bfloat16 h; u16 u; } cv;
    cv.h = h;
    return cv.u;
}

// ---------------- setup: A0, A1, Bb, conj(C) ----------------
__global__ __launch_bounds__(256) void prep_kernel(
    const float* lre, const float* lim, const float* pre, const float* pim,
    const float* bre, const float* bim, const float* cre, const float* cim,
    const float* lstep) {
    __shared__ cplx lam[NST], P[NST], Bv[NST], dd[NST];
    __shared__ cplx s2inv, S3;
    __shared__ float twodt;
    int tid = threadIdx.x;
    if (tid < NST) {
        lam[tid] = { lre[tid], lim[tid] };
        P[tid] = { pre[tid], pim[tid] };
        Bv[tid] = { bre[tid], bim[tid] };
    }
    if (tid == 0) twodt = 2.0f / expf(lstep[0]);
    __syncthreads();
    if (tid < NST) {
        // dd = 1 / (2/step - Lam)
        cplx w = { twodt - lam[tid].x, -lam[tid].y };
        float den = w.x * w.x + w.y * w.y;
        dd[tid] = { w.x / den, -w.y / den };
    }
    __syncthreads();
    if (tid == 0) {
        cplx s = { 1.f, 0.f };   // 1 + Qc Dd P
        cplx s3 = { 0.f, 0.f };  // Qc Dd B  (for Bb closed form)
        for (int n = 0; n < NST; n++) {
            float pp = P[n].x * P[n].x + P[n].y * P[n].y;
            s.x += dd[n].x * pp;
            s.y += dd[n].y * pp;
            cplx pc = { P[n].x, -P[n].y };
            s3 = cmadd(s3, pc, cmul(dd[n], Bv[n]));
        }
        float den = s.x * s.x + s.y * s.y;
        s2inv = { s.x / den, -s.y / den };
        S3 = s3;
    }
    __syncthreads();
    for (int o = tid; o < NST * NST; o += 256) {
        int r = o >> 6, c = o & 63;
        cplx pc_conj = { P[c].x, -P[c].y };
        // A0 = (2/step) I + diag(Lam) - P P^H
        cplx a0 = cmul(P[r], pc_conj);
        a0 = { -a0.x, -a0.y };
        if (r == c) { a0.x += twodt + lam[r].x; a0.y += lam[r].y; }
        g_A0[o] = a0;
        // A1 = Dd - Dd P P^H Dd / (1 + Qc Dd P)
        cplx t1 = cmul(dd[r], P[r]);
        t1 = cmul(t1, pc_conj);
        t1 = cmul(t1, dd[c]);
        t1 = cmul(t1, s2inv);
        cplx a1 = { -t1.x, -t1.y };
        if (r == c) { a1.x += dd[r].x; a1.y += dd[r].y; }
        g_A1[o] = a1;
    }
    if (tid < NST) {
        // Bb = 2 * A1 @ B = 2*( dd*B - dd*P*s2inv*S3 )
        cplx t = cmul(dd[tid], Bv[tid]);
        cplx u = cmul(cmul(dd[tid], P[tid]), cmul(s2inv, S3));
        g_Bb[tid] = { 2.f * (t.x - u.x), 2.f * (t.y - u.y) };
    }
    if (tid >= 64 && tid < 128) {
        int n = tid - 64;
        g_c[n] = { cre[n], -cim[n] };
    }
}

// ---------------- 64x64 complex matmul: D = A @ B ----------------
// ja: -1 -> g_A1, else g_S[ja]; jb: -1 -> g_A0, else g_S[jb]; dst g_S[jd]
__global__ __launch_bounds__(256) void square_step(int ja, int jb, int jd) {
    const cplx* A = (ja < 0) ? g_A1 : g_S[ja];
    const cplx* B = (jb < 0) ? g_A0 : g_S[jb];
    int gid = blockIdx.x * 256 + threadIdx.x;  // 4096
    int r = gid >> 6, c = gid & 63;
    cplx acc = { 0.f, 0.f };
#pragma unroll 8
    for (int k = 0; k < NST; k++) acc = cmadd(acc, A[r * NST + k], B[k * NST + c]);
    g_S[jd][gid] = acc;
}

// ---------------- finish: V doubling, Neumann Cb, L chain, k assembly ----------------
__global__ __launch_bounds__(1024) void finish_kernel() {
    __shared__ cplx V[NST][NST + 1];  // V[b][n] = (Ab^b Bb)[n]
    __shared__ cplx zv[NST], znew[NST], cv[NST], Lv[NST], Lnew[NST];
    int tid = threadIdx.x;
    if (tid < NST) V[0][tid] = g_Bb[tid];
    else if (tid < 128) {
        int n = tid - 64;
        cplx c = g_c[n];
        cv[n] = c;
        zv[n] = c;
    }
    __syncthreads();
    // V doubling: uses S[j] = Ab^(2^j), j = 0..5
    for (int j = 0; j < 6; j++) {
        int cols = 1 << j;
        const cplx* Sj = g_S[j];
        for (int o = tid; o < cols * NST; o += 1024) {
            int t = o >> 6, r = o & 63;
            cplx s = { 0.f, 0.f };
#pragma unroll 8
            for (int k = 0; k < NST; k++) s = cmadd(s, Sj[r * NST + k], V[t][k]);
            V[cols + t][r] = s;
        }
        __syncthreads();
    }
    // z chain: z <- R^T z, 32 times  (R = S[6] = Ab^64) => z = (Ab^T)^2048 conj(C)
    int i16 = tid >> 4, p = tid & 15;
    const cplx* R = g_S[6];
    for (int it = 0; it < 32; it++) {
        cplx s = { 0.f, 0.f };
#pragma unroll
        for (int jj = 0; jj < 4; jj++) {
            int j = p * 4 + jj;
            s = cmadd(s, R[j * NST + i16], zv[j]);
        }
        s.x += __shfl_xor(s.x, 1); s.y += __shfl_xor(s.y, 1);
        s.x += __shfl_xor(s.x, 2); s.y += __shfl_xor(s.y, 2);
        s.x += __shfl_xor(s.x, 4); s.y += __shfl_xor(s.y, 4);
        s.x += __shfl_xor(s.x, 8); s.y += __shfl_xor(s.y, 8);
        if (p == 0) znew[i16] = s;
        __syncthreads();
        if (tid < NST) zv[tid] = znew[tid];
        __syncthreads();
    }
    // Cb = conj(C) + z   (Neumann 1 term; ||Ab^2048|| ~ 0.6%, residual ~3e-5)
    if (tid < NST) Lv[tid] = { cv[tid].x + zv[tid].x, cv[tid].y + zv[tid].y };
    __syncthreads();
    // L chain + k assembly: k[64a+b] = Re(L_a . V_b),  L_{a+1} = R^T L_a
    for (int a = 0; a < 32; a++) {
        int b = i16;
        float kr = 0.f;
#pragma unroll
        for (int jj = 0; jj < 4; jj++) {
            int n = p * 4 + jj;
            kr += Lv[n].x * V[b][n].x - Lv[n].y * V[b][n].y;
        }
        kr += __shfl_xor(kr, 1);
        kr += __shfl_xor(kr, 2);
        kr += __shfl_xor(kr, 4);
        kr += __shfl_xor(kr, 8);
        if (p == 0) g_k[a * 64 + b] = kr;
        cplx s = { 0.f, 0.f };
        int c = i16;
#pragma unroll
        for (int jj = 0; jj < 4; jj++) {
            int r = p * 4 + jj;
            s = cmadd(s, Lv[r], R[r * NST + c]);
        }
        s.x += __shfl_xor(s.x, 1); s.y += __shfl_xor(s.y, 1);
        s.x += __shfl_xor(s.x, 2); s.y += __shfl_xor(s.y, 2);
        s.x += __shfl_xor(s.x, 4); s.y += __shfl_xor(s.y, 4);
        s.x += __shfl_xor(s.x, 8); s.y += __shfl_xor(s.y, 8);
        if (p == 0) Lnew[c] = s;
        __syncthreads();
        if (tid < NST) Lv[tid] = Lnew[tid];
        __syncthreads();
    }
}

// ---------------- conversions ----------------
__global__ __launch_bounds__(256) void convert_x(const float* x) {
    __shared__ float tile[64][65];
    int tid = threadIdx.x;
    int bi = blockIdx.x;
    int lt = bi >> 3, ht = bi & 7;
#pragma unroll
    for (int i = 0; i < 16; i++) {
        int idx = i * 256 + tid;
        int r = idx >> 6, c = idx & 63;
        tile[r][c] = x[(lt * 64 + r) * HID + ht * 64 + c];
    }
    __syncthreads();
#pragma unroll
    for (int i = 0; i < 16; i++) {
        int idx = i * 256 + tid;
        int r = idx >> 6, c = idx & 63;
        g_Xt[(ht * 64 + r) * L_SEQ + lt * 64 + c] = f2bf(tile[c][r]);
    }
}

__global__ __launch_bounds__(256) void convert_w(const float* w1, const float* w2) {
    int t = blockIdx.x * 256 + threadIdx.x;  // 131072 threads; 65536 float4 per matrix
    const float* src = (t < 65536) ? w1 : w2;
    u16* dst = (t < 65536) ? g_W1 : g_W2;
    int idx = (t < 65536) ? t : (t - 65536);
    float4 v = ((const float4*)src)[idx];
    u16 o0 = f2bf(v.x), o1 = f2bf(v.y), o2 = f2bf(v.z), o3 = f2bf(v.w);
    u16x8 dummy;  // store 4 via u64 pack
    unsigned long long pk = (unsigned long long)o0 | ((unsigned long long)o1 << 16) |
                            ((unsigned long long)o2 << 32) | ((unsigned long long)o3 << 48);
    ((unsigned long long*)dst)[idx] = pk;
    (void)dummy;
}

__global__ __launch_bounds__(256) void build_T() {
    int gid = blockIdx.x * 256 + threadIdx.x;  // 524288
    int o = gid * 8;
    int i = o >> 11, j0 = o & 2047;
    u16x8 v;
#pragma unroll
    for (int q = 0; q < 8; q++) {
        int d = i - (j0 + q);
        float val = (d >= 0) ? g_k[d] : 0.f;
        v[q] = f2bf(val);
    }
    *(u16x8*)&g_T[o] = v;
}

// ---------------- conv GEMM: Y = T @ X  (triangular), epilogue gelu -> H ----------------
__global__ __launch_bounds__(256) void conv_gemm() {
    __shared__ __align__(16) u16 As[128 * 64];
    __shared__ __align__(16) u16 Bs[128 * 64];
    int tid = threadIdx.x, l = tid & 63, w = tid >> 6;
    int wm = w >> 1, wn = w & 1;
    int bm = blockIdx.x >> 2, bn = blockIdx.x & 3;
    f32x4 acc[4][4] = {};
    int nkb = 2 * (bm + 1);  // triangular: K <= 128*(bm+1)
    for (int kb = 0; kb < nkb; kb++) {
        int k0 = kb * 64;
#pragma unroll
        for (int i = 0; i < 4; i++) {
            int slot = i * 256 + tid;
            int row = slot >> 3;
            int kk = (slot & 7) * 8;
            ((u32x4*)As)[slot] = *(const u32x4*)&g_T[(bm * 128 + row) * L_SEQ + k0 + kk];
            ((u32x4*)Bs)[slot] = *(const u32x4*)&g_Xt[(bn * 128 + row) * L_SEQ + k0 + kk];
        }
        __syncthreads();
#pragma unroll
        for (int ks = 0; ks < 2; ks++) {
            s16x8 af[4], bf[4];
            int ko = ks * 32 + (l >> 4) * 8;
#pragma unroll
            for (int m = 0; m < 4; m++)
                af[m] = *(const s16x8*)&As[(wm * 64 + m * 16 + (l & 15)) * 64 + ko];
#pragma unroll
            for (int n = 0; n < 4; n++)
                bf[n] = *(const s16x8*)&Bs[(wn * 64 + n * 16 + (l & 15)) * 64 + ko];
#pragma unroll
            for (int m = 0; m < 4; m++)
#pragma unroll
                for (int n = 0; n < 4; n++)
                    acc[m][n] = __builtin_amdgcn_mfma_f32_16x16x32_bf16(af[m], bf[n], acc[m][n], 0, 0, 0);
        }
        __syncthreads();
    }
#pragma unroll
    for (int m = 0; m < 4; m++)
#pragma unroll
        for (int n = 0; n < 4; n++)
#pragma unroll
            for (int r4 = 0; r4 < 4; r4++) {
                int row = bm * 128 + wm * 64 + m * 16 + (l >> 4) * 4 + r4;
                int col = bn * 128 + wn * 64 + n * 16 + (l & 15);
                float y = acc[m][n][r4];
                float inner = 0.79788456080286535588f * (y + 0.044715f * y * y * y);
                float h = 0.5f * y * (1.f + tanhf(inner));
                g_H[row * HID + col] = f2bf(h);
            }
}

// ---------------- FFN: out = x + (H@W1^T + b1) * sigmoid(H@W2^T + b2) ----------------
__global__ __launch_bounds__(256) void ffn_gemm(const float* x, const float* b1,
                                                const float* b2, float* out) {
    __shared__ __align__(16) u16 As[128 * 64];
    __shared__ __align__(16) u16 B1s[128 * 64];
    __shared__ __align__(16) u16 B2s[128 * 64];
    int tid = threadIdx.x, l = tid & 63, w = tid >> 6;
    int wm = w >> 1, wn = w & 1;
    int bm = blockIdx.x >> 2, bn = blockIdx.x & 3;
    f32x4 acc1[4][4] = {}, acc2[4][4] = {};
    for (int kb = 0; kb < 8; kb++) {
        int k0 = kb * 64;
#pragma unroll
        for (int i = 0; i < 4; i++) {
            int slot = i * 256 + tid;
            int row = slot >> 3;
            int kk = (slot & 7) * 8;
            ((u32x4*)As)[slot] = *(const u32x4*)&g_H[(bm * 128 + row) * HID + k0 + kk];
            ((u32x4*)B1s)[slot] = *(const u32x4*)&g_W1[(bn * 128 + row) * HID + k0 + kk];
            ((u32x4*)B2s)[slot] = *(const u32x4*)&g_W2[(bn * 128 + row) * HID + k0 + kk];
        }
        __syncthreads();
#pragma unroll
        for (int ks = 0; ks < 2; ks++) {
            s16x8 af[4], b1f[4], b2f[4];
            int ko = ks * 32 + (l >> 4) * 8;
#pragma unroll
            for (int m = 0; m < 4; m++)
                af[m] = *(const s16x8*)&As[(wm * 64 + m * 16 + (l & 15)) * 64 + ko];
#pragma unroll
            for (int n = 0; n < 4; n++) {
                b1f[n] = *(const s16x8*)&B1s[(wn * 64 + n * 16 + (l & 15)) * 64 + ko];
                b2f[n] = *(const s16x8*)&B2s[(wn * 64 + n * 16 + (l & 15)) * 64 + ko];
            }
#pragma unroll
            for (int m = 0; m < 4; m++)
#pragma unroll
                for (int n = 0; n < 4; n++) {
                    acc1[m][n] = __builtin_amdgcn_mfma_f32_16x16x32_bf16(af[m], b1f[n], acc1[m][n], 0, 0, 0);
                    acc2[m][n] = __builtin_amdgcn_mfma_f32_16x16x32_bf16(af[m], b2f[n], acc2[m][n], 0, 0, 0);
                }
        }
        __syncthreads();
    }
#pragma unroll
    for (int m = 0; m < 4; m++)
#pragma unroll
        for (int n = 0; n < 4; n++)
#pragma unroll
            for (int r4 = 0; r4 < 4; r4++) {
                int row = bm * 128 + wm * 64 + m * 16 + (l >> 4) * 4 + r4;
                int col = bn * 128 + wn * 64 + n * 16 + (l & 15);
                float g1 = acc1[m][n][r4] + b1[col];
                float g2 = acc2[m][n][r4] + b2[col];
                float sg = 1.f / (1.f + expf(-g2));
                out[row * HID + col] = x[row * HID + col] + g1 * sg;
            }
}

extern "C" void kernel_launch(void* const* d_in, const int* in_sizes, int n_in,
                              void* d_out, int out_size, void* d_ws, size_t ws_size,
                              hipStream_t stream) {
    const float* x = (const float*)d_in[0];
    const float* lre = (const float*)d_in[1];
    const float* lim = (const float*)d_in[2];
    const float* pre = (const float*)d_in[3];
    const float* pim = (const float*)d_in[4];
    const float* bre = (const float*)d_in[5];
    const float* bim = (const float*)d_in[6];
    const float* cre = (const float*)d_in[7];
    const float* cim = (const float*)d_in[8];
    const float* lstep = (const float*)d_in[9];
    const float* w1 = (const float*)d_in[10];
    const float* b1 = (const float*)d_in[11];
    const float* w2 = (const float*)d_in[12];
    const float* b2 = (const float*)d_in[13];
    float* out = (float*)d_out;

    prep_kernel<<<1, 256, 0, stream>>>(lre, lim, pre, pim, bre, bim, cre, cim, lstep);
    square_step<<<16, 256, 0, stream>>>(-1, -1, 0);  // Ab = A1 @ A0
    square_step<<<16, 256, 0, stream>>>(0, 0, 1);    // Ab^2
    square_step<<<16, 256, 0, stream>>>(1, 1, 2);    // Ab^4
    square_step<<<16, 256, 0, stream>>>(2, 2, 3);    // Ab^8
    square_step<<<16, 256, 0, stream>>>(3, 3, 4);    // Ab^16
    square_step<<<16, 256, 0, stream>>>(4, 4, 5);    // Ab^32
    square_step<<<16, 256, 0, stream>>>(5, 5, 6);    // Ab^64
    finish_kernel<<<1, 1024, 0, stream>>>();
    convert_x<<<256, 256, 0, stream>>>(x);
    convert_w<<<512, 256, 0, stream>>>(w1, w2);
    build_T<<<2048, 256, 0, stream>>>();
    conv_gemm<<<64, 256, 0, stream>>>();
    ffn_gemm<<<64, 256, 0, stream>>>(x, b1, b2, out);
}

// Round 2
// 168.428 us; speedup vs baseline: 2.1577x; 2.1577x over previous
//
#include <hip/hip_runtime.h>
#include <hip/hip_bf16.h>

typedef unsigned short u16;
typedef short s16x8 __attribute__((ext_vector_type(8)));
typedef u16 u16x8 __attribute__((ext_vector_type(8)));
typedef unsigned int u32x4 __attribute__((ext_vector_type(4)));
typedef float f32x4 __attribute__((ext_vector_type(4)));

struct cplx { float x, y; };

#define L_SEQ 2048
#define HID 512
#define NST 64

// ---------------- device scratch (fully rewritten every call) ----------------
__device__ __align__(16) cplx g_S[11][NST * NST];  // S[j] = Ab^(2^j)
__device__ __align__(16) cplx g_Bb[NST];
__device__ __align__(16) cplx g_c[NST];            // conj(C)
__device__ __align__(16) float g_k[L_SEQ];
__device__ __align__(16) u16 g_T[L_SEQ * L_SEQ];   // bf16 Toeplitz [i][j] = k[i-j]
__device__ __align__(16) u16 g_Xt[HID * L_SEQ];    // bf16 X^T  [h][l]
__device__ __align__(16) u16 g_W1[HID * HID];      // bf16 [n][k]
__device__ __align__(16) u16 g_W2[HID * HID];
__device__ __align__(16) u16 g_H[L_SEQ * HID];     // bf16 gelu(conv out) [l][h]

__device__ __forceinline__ cplx cmul(cplx a, cplx b) {
    return { a.x * b.x - a.y * b.y, a.x * b.y + a.y * b.x };
}
__device__ __forceinline__ cplx cmadd(cplx s, cplx a, cplx b) {
    s.x += a.x * b.x - a.y * b.y;
    s.y += a.x * b.y + a.y * b.x;
    return s;
}
__device__ __forceinline__ u16 f2bf(float f) {
    union { __hip_bfloat16 h; u16 u; } cv;
    cv.h = __float2bfloat16(f);
    return cv.u;
}

// ---------------- setup + Ab = A1@A0 (prep folded into every block) ----------------
__global__ __launch_bounds__(256) void square0(
    const float* lre, const float* lim, const float* pre, const float* pim,
    const float* bre, const float* bim, const float* cre, const float* cim,
    const float* lstep) {
    __shared__ cplx lam[NST], P[NST], Bv[NST], dd[NST];
    __shared__ cplx s2inv, S3;
    __shared__ float twodt;
    __shared__ cplx A0s[NST][NST + 2];
    __shared__ cplx A1s[4][NST];
    int tid = threadIdx.x;
    if (tid < NST) {
        lam[tid] = { lre[tid], lim[tid] };
        P[tid] = { pre[tid], pim[tid] };
        Bv[tid] = { bre[tid], bim[tid] };
    }
    if (tid == 0) twodt = 2.0f / expf(lstep[0]);
    __syncthreads();
    if (tid < NST) {
        cplx w = { twodt - lam[tid].x, -lam[tid].y };
        float den = w.x * w.x + w.y * w.y;
        dd[tid] = { w.x / den, -w.y / den };
    }
    __syncthreads();
    if (tid == 0) {
        cplx s = { 1.f, 0.f };
        cplx s3 = { 0.f, 0.f };
        for (int n = 0; n < NST; n++) {
            float pp = P[n].x * P[n].x + P[n].y * P[n].y;
            s.x += dd[n].x * pp;
            s.y += dd[n].y * pp;
            cplx pc = { P[n].x, -P[n].y };
            s3 = cmadd(s3, pc, cmul(dd[n], Bv[n]));
        }
        float den = s.x * s.x + s.y * s.y;
        s2inv = { s.x / den, -s.y / den };
        S3 = s3;
    }
    __syncthreads();
    // A0 full into LDS
    for (int o = tid; o < NST * NST; o += 256) {
        int r = o >> 6, c = o & 63;
        cplx pc_conj = { P[c].x, -P[c].y };
        cplx a0 = cmul(P[r], pc_conj);
        a0 = { -a0.x, -a0.y };
        if (r == c) { a0.x += twodt + lam[r].x; a0.y += lam[r].y; }
        A0s[r][c] = a0;
    }
    // A1 rows of this block
    int rbase = blockIdx.x * 4;
    {
        int rr = tid >> 6, c = tid & 63;
        int r = rbase + rr;
        cplx pc_conj = { P[c].x, -P[c].y };
        cplx t1 = cmul(dd[r], P[r]);
        t1 = cmul(t1, pc_conj);
        t1 = cmul(t1, dd[c]);
        t1 = cmul(t1, s2inv);
        cplx a1 = { -t1.x, -t1.y };
        if (r == c) { a1.x += dd[r].x; a1.y += dd[r].y; }
        A1s[rr][c] = a1;
    }
    if (blockIdx.x == 0 && tid < NST) {
        cplx t = cmul(dd[tid], Bv[tid]);
        cplx u = cmul(cmul(dd[tid], P[tid]), cmul(s2inv, S3));
        g_Bb[tid] = { 2.f * (t.x - u.x), 2.f * (t.y - u.y) };
        g_c[tid] = { cre[tid], -cim[tid] };
    }
    __syncthreads();
    int rr = tid >> 6, c = tid & 63;
    cplx acc = { 0.f, 0.f };
#pragma unroll 8
    for (int k = 0; k < NST; k++) acc = cmadd(acc, A1s[rr][k], A0s[k][c]);
    g_S[0][(rbase + rr) * NST + c] = acc;
}

// ---------------- S[jd] = S[js] @ S[js] ----------------
__global__ __launch_bounds__(256) void square_step(int js, int jd) {
    const cplx* A = g_S[js];
    int gid = blockIdx.x * 256 + threadIdx.x;  // 4096
    int r = gid >> 6, c = gid & 63;
    cplx acc = { 0.f, 0.f };
#pragma unroll 8
    for (int k = 0; k < NST; k++) acc = cmadd(acc, A[r * NST + k], A[k * NST + c]);
    g_S[jd][gid] = acc;
}

// ---------------- finish: parallel doubling stages + k assembly ----------------
#define VST 66
__global__ __launch_bounds__(1024) void finish_k() {
    __shared__ cplx V[64][VST];   // V[b] = Ab^b Bb
    __shared__ cplx U[32][VST];   // U[a] = (R^a)^T Cb, R = Ab^64
    __shared__ cplx cv[NST], t1v[NST];
    int tid = threadIdx.x;
    int r = tid >> 4, kl = tid & 15;  // 64 outputs x 16 k-lanes
    if (tid < NST) {
        V[0][tid] = g_Bb[tid];
        cv[tid] = g_c[tid];
    }
    __syncthreads();
    // V doubling: V[2^j + t] = S[j] @ V[t]
    for (int j = 0; j < 6; j++) {
        int T = 1 << j;
        const cplx* M = g_S[j];
        int mb = r * NST + kl * 4;
        cplx m0 = M[mb], m1 = M[mb + 1], m2 = M[mb + 2], m3 = M[mb + 3];
        for (int t = 0; t < T; t++) {
            cplx acc = { 0.f, 0.f };
            acc = cmadd(acc, m0, V[t][kl * 4 + 0]);
            acc = cmadd(acc, m1, V[t][kl * 4 + 1]);
            acc = cmadd(acc, m2, V[t][kl * 4 + 2]);
            acc = cmadd(acc, m3, V[t][kl * 4 + 3]);
            acc.x += __shfl_xor(acc.x, 1); acc.y += __shfl_xor(acc.y, 1);
            acc.x += __shfl_xor(acc.x, 2); acc.y += __shfl_xor(acc.y, 2);
            acc.x += __shfl_xor(acc.x, 4); acc.y += __shfl_xor(acc.y, 4);
            acc.x += __shfl_xor(acc.x, 8); acc.y += __shfl_xor(acc.y, 8);
            if (kl == 0) V[T + t][r] = acc;
        }
        __syncthreads();
    }
    // z = (S10^T)^2 conjC ;  Cb = conjC + z -> U[0]
    {
        const cplx* M = g_S[10];
        int mb = (kl * 4) * NST + r;
        cplx m0 = M[mb], m1 = M[mb + NST], m2 = M[mb + 2 * NST], m3 = M[mb + 3 * NST];
        cplx acc = { 0.f, 0.f };
        acc = cmadd(acc, m0, cv[kl * 4 + 0]);
        acc = cmadd(acc, m1, cv[kl * 4 + 1]);
        acc = cmadd(acc, m2, cv[kl * 4 + 2]);
        acc = cmadd(acc, m3, cv[kl * 4 + 3]);
        acc.x += __shfl_xor(acc.x, 1); acc.y += __shfl_xor(acc.y, 1);
        acc.x += __shfl_xor(acc.x, 2); acc.y += __shfl_xor(acc.y, 2);
        acc.x += __shfl_xor(acc.x, 4); acc.y += __shfl_xor(acc.y, 4);
        acc.x += __shfl_xor(acc.x, 8); acc.y += __shfl_xor(acc.y, 8);
        if (kl == 0) t1v[r] = acc;
        __syncthreads();
        acc = { 0.f, 0.f };
        acc = cmadd(acc, m0, t1v[kl * 4 + 0]);
        acc = cmadd(acc, m1, t1v[kl * 4 + 1]);
        acc = cmadd(acc, m2, t1v[kl * 4 + 2]);
        acc = cmadd(acc, m3, t1v[kl * 4 + 3]);
        acc.x += __shfl_xor(acc.x, 1); acc.y += __shfl_xor(acc.y, 1);
        acc.x += __shfl_xor(acc.x, 2); acc.y += __shfl_xor(acc.y, 2);
        acc.x += __shfl_xor(acc.x, 4); acc.y += __shfl_xor(acc.y, 4);
        acc.x += __shfl_xor(acc.x, 8); acc.y += __shfl_xor(acc.y, 8);
        if (kl == 0) U[0][r] = { cv[r].x + acc.x, cv[r].y + acc.y };
        __syncthreads();
    }
    // U doubling: U[2^j + t] = S[6+j]^T @ U[t]
    for (int j = 0; j < 5; j++) {
        int T = 1 << j;
        const cplx* M = g_S[6 + j];
        int mb = (kl * 4) * NST + r;
        cplx m0 = M[mb], m1 = M[mb + NST], m2 = M[mb + 2 * NST], m3 = M[mb + 3 * NST];
        for (int t = 0; t < T; t++) {
            cplx acc = { 0.f, 0.f };
            acc = cmadd(acc, m0, U[t][kl * 4 + 0]);
            acc = cmadd(acc, m1, U[t][kl * 4 + 1]);
            acc = cmadd(acc, m2, U[t][kl * 4 + 2]);
            acc = cmadd(acc, m3, U[t][kl * 4 + 3]);
            acc.x += __shfl_xor(acc.x, 1); acc.y += __shfl_xor(acc.y, 1);
            acc.x += __shfl_xor(acc.x, 2); acc.y += __shfl_xor(acc.y, 2);
            acc.x += __shfl_xor(acc.x, 4); acc.y += __shfl_xor(acc.y, 4);
            acc.x += __shfl_xor(acc.x, 8); acc.y += __shfl_xor(acc.y, 8);
            if (kl == 0) U[T + t][r] = acc;
        }
        __syncthreads();
    }
    // k[64a + b] = Re(U[a] . V[b])
    for (int o = tid; o < L_SEQ; o += 1024) {
        int a = o >> 6, b = o & 63;
        float kr = 0.f;
#pragma unroll 8
        for (int n = 0; n < NST; n++)
            kr += U[a][n].x * V[b][n].x - U[a][n].y * V[b][n].y;
        g_k[o] = kr;
    }
}

// ---------------- fused conversions + Toeplitz build ----------------
__global__ __launch_bounds__(256) void fused_convert(const float* x, const float* w1,
                                                     const float* w2) {
    __shared__ float tile[64][65];
    int tid = threadIdx.x;
    int b = blockIdx.x;
    if (b < 256) {
        // X -> bf16 X^T
        int lt = b >> 3, ht = b & 7;
#pragma unroll
        for (int i = 0; i < 16; i++) {
            int idx = i * 256 + tid;
            int r = idx >> 6, c = idx & 63;
            tile[r][c] = x[(lt * 64 + r) * HID + ht * 64 + c];
        }
        __syncthreads();
#pragma unroll
        for (int i = 0; i < 16; i++) {
            int idx = i * 256 + tid;
            int r = idx >> 6, c = idx & 63;
            g_Xt[(ht * 64 + r) * L_SEQ + lt * 64 + c] = f2bf(tile[c][r]);
        }
    } else if (b < 768) {
        // W1/W2 -> bf16
        int t = (b - 256) * 256 + tid;  // 131072
        const float* src = (t < 65536) ? w1 : w2;
        u16* dst = (t < 65536) ? g_W1 : g_W2;
        int idx = (t < 65536) ? t : (t - 65536);
        float4 v = ((const float4*)src)[idx];
        unsigned long long pk = (unsigned long long)f2bf(v.x) |
                                ((unsigned long long)f2bf(v.y) << 16) |
                                ((unsigned long long)f2bf(v.z) << 32) |
                                ((unsigned long long)f2bf(v.w) << 48);
        ((unsigned long long*)dst)[idx] = pk;
    } else {
        // Toeplitz T[i][j] = k[i-j]
        int gid = (b - 768) * 256 + tid;  // 524288
        int o = gid * 8;
        int i = o >> 11, j0 = o & 2047;
        u16x8 v;
#pragma unroll
        for (int q = 0; q < 8; q++) {
            int d = i - (j0 + q);
            v[q] = f2bf((d >= 0) ? g_k[d] : 0.f);
        }
        *(u16x8*)&g_T[o] = v;
    }
}

// ---------------- conv GEMM: Y = T @ X (triangular), gelu -> H ----------------
__global__ __launch_bounds__(256) void conv_gemm() {
    __shared__ __align__(16) u16 As[64 * 64];
    __shared__ __align__(16) u16 Bs[64 * 64];
    int tid = threadIdx.x, l = tid & 63, w = tid >> 6;
    int wm = w >> 1, wn = w & 1;
    int bm = blockIdx.x >> 3, bn = blockIdx.x & 7;  // 32 x 8
    f32x4 acc[2][2] = {};
    int nkb = bm + 1;  // triangular
    for (int kb = 0; kb < nkb; kb++) {
        int k0 = kb * 64;
#pragma unroll
        for (int i = 0; i < 2; i++) {
            int slot = i * 256 + tid;
            int row = slot >> 3, kc = slot & 7;
            int sidx = row * 8 + (kc ^ (row & 7));  // chunk swizzle
            ((u32x4*)As)[sidx] = *(const u32x4*)&g_T[(bm * 64 + row) * L_SEQ + k0 + kc * 8];
            ((u32x4*)Bs)[sidx] = *(const u32x4*)&g_Xt[(bn * 64 + row) * L_SEQ + k0 + kc * 8];
        }
        __syncthreads();
#pragma unroll
        for (int ks = 0; ks < 2; ks++) {
            s16x8 af[2], bf[2];
#pragma unroll
            for (int m = 0; m < 2; m++) {
                int row = wm * 32 + m * 16 + (l & 15);
                int chunk = (ks * 4 + (l >> 4)) ^ (row & 7);
                af[m] = *(const s16x8*)&As[row * 64 + chunk * 8];
            }
#pragma unroll
            for (int n = 0; n < 2; n++) {
                int col = wn * 32 + n * 16 + (l & 15);
                int chunk = (ks * 4 + (l >> 4)) ^ (col & 7);
                bf[n] = *(const s16x8*)&Bs[col * 64 + chunk * 8];
            }
#pragma unroll
            for (int m = 0; m < 2; m++)
#pragma unroll
                for (int n = 0; n < 2; n++)
                    acc[m][n] = __builtin_amdgcn_mfma_f32_16x16x32_bf16(af[m], bf[n], acc[m][n], 0, 0, 0);
        }
        __syncthreads();
    }
#pragma unroll
    for (int m = 0; m < 2; m++)
#pragma unroll
        for (int n = 0; n < 2; n++)
#pragma unroll
            for (int r4 = 0; r4 < 4; r4++) {
                int row = bm * 64 + wm * 32 + m * 16 + (l >> 4) * 4 + r4;
                int col = bn * 64 + wn * 32 + n * 16 + (l & 15);
                float y = acc[m][n][r4];
                float u = 1.5957691216057308f * (y + 0.044715f * y * y * y);  // 2*sqrt(2/pi)*(...)
                float th = 1.f - 2.f / (__expf(u) + 1.f);                     // tanh
                g_H[row * HID + col] = f2bf(0.5f * y * (1.f + th));
            }
}

// ---------------- FFN: out = x + (H@W1^T + b1) * sigmoid(H@W2^T + b2) ----------------
__global__ __launch_bounds__(256) void ffn_gemm(const float* x, const float* b1,
                                                const float* b2, float* out) {
    __shared__ __align__(16) u16 As[64 * 64];
    __shared__ __align__(16) u16 B1s[64 * 64];
    __shared__ __align__(16) u16 B2s[64 * 64];
    int tid = threadIdx.x, l = tid & 63, w = tid >> 6;
    int wm = w >> 1, wn = w & 1;
    int bm = blockIdx.x >> 3, bn = blockIdx.x & 7;  // 32 x 8
    f32x4 acc1[2][2] = {}, acc2[2][2] = {};
    for (int kb = 0; kb < 8; kb++) {
        int k0 = kb * 64;
#pragma unroll
        for (int i = 0; i < 2; i++) {
            int slot = i * 256 + tid;
            int row = slot >> 3, kc = slot & 7;
            int sidx = row * 8 + (kc ^ (row & 7));
            ((u32x4*)As)[sidx] = *(const u32x4*)&g_H[(bm * 64 + row) * HID + k0 + kc * 8];
            ((u32x4*)B1s)[sidx] = *(const u32x4*)&g_W1[(bn * 64 + row) * HID + k0 + kc * 8];
            ((u32x4*)B2s)[sidx] = *(const u32x4*)&g_W2[(bn * 64 + row) * HID + k0 + kc * 8];
        }
        __syncthreads();
#pragma unroll
        for (int ks = 0; ks < 2; ks++) {
            s16x8 af[2], b1f[2], b2f[2];
#pragma unroll
            for (int m = 0; m < 2; m++) {
                int row = wm * 32 + m * 16 + (l & 15);
                int chunk = (ks * 4 + (l >> 4)) ^ (row & 7);
                af[m] = *(const s16x8*)&As[row * 64 + chunk * 8];
            }
#pragma unroll
            for (int n = 0; n < 2; n++) {
                int col = wn * 32 + n * 16 + (l & 15);
                int chunk = (ks * 4 + (l >> 4)) ^ (col & 7);
                b1f[n] = *(const s16x8*)&B1s[col * 64 + chunk * 8];
                b2f[n] = *(const s16x8*)&B2s[col * 64 + chunk * 8];
            }
#pragma unroll
            for (int m = 0; m < 2; m++)
#pragma unroll
                for (int n = 0; n < 2; n++) {
                    acc1[m][n] = __builtin_amdgcn_mfma_f32_16x16x32_bf16(af[m], b1f[n], acc1[m][n], 0, 0, 0);
                    acc2[m][n] = __builtin_amdgcn_mfma_f32_16x16x32_bf16(af[m], b2f[n], acc2[m][n], 0, 0, 0);
                }
        }
        __syncthreads();
    }
#pragma unroll
    for (int m = 0; m < 2; m++)
#pragma unroll
        for (int n = 0; n < 2; n++)
#pragma unroll
            for (int r4 = 0; r4 < 4; r4++) {
                int row = bm * 64 + wm * 32 + m * 16 + (l >> 4) * 4 + r4;
                int col = bn * 64 + wn * 32 + n * 16 + (l & 15);
                float g1 = acc1[m][n][r4] + b1[col];
                float g2 = acc2[m][n][r4] + b2[col];
                float sg = 1.f / (1.f + __expf(-g2));
                out[row * HID + col] = x[row * HID + col] + g1 * sg;
            }
}

extern "C" void kernel_launch(void* const* d_in, const int* in_sizes, int n_in,
                              void* d_out, int out_size, void* d_ws, size_t ws_size,
                              hipStream_t stream) {
    const float* x = (const float*)d_in[0];
    const float* lre = (const float*)d_in[1];
    const float* lim = (const float*)d_in[2];
    const float* pre = (const float*)d_in[3];
    const float* pim = (const float*)d_in[4];
    const float* bre = (const float*)d_in[5];
    const float* bim = (const float*)d_in[6];
    const float* cre = (const float*)d_in[7];
    const float* cim = (const float*)d_in[8];
    const float* lstep = (const float*)d_in[9];
    const float* w1 = (const float*)d_in[10];
    const float* b1 = (const float*)d_in[11];
    const float* w2 = (const float*)d_in[12];
    const float* b2 = (const float*)d_in[13];
    float* out = (float*)d_out;

    square0<<<16, 256, 0, stream>>>(lre, lim, pre, pim, bre, bim, cre, cim, lstep);
    for (int j = 1; j <= 10; j++)
        square_step<<<16, 256, 0, stream>>>(j - 1, j);  // S[j] = Ab^(2^j)
    finish_k<<<1, 1024, 0, stream>>>();
    fused_convert<<<2816, 256, 0, stream>>>(x, w1, w2);
    conv_gemm<<<256, 256, 0, stream>>>();
    ffn_gemm<<<256, 256, 0, stream>>>(x, b1, b2, out);
}

// Round 3
// 107.001 us; speedup vs baseline: 3.3964x; 1.5741x over previous
//
#include <hip/hip_runtime.h>
#include <hip/hip_bf16.h>

typedef unsigned short u16;
typedef short s16x8 __attribute__((ext_vector_type(8)));
typedef u16 u16x8 __attribute__((ext_vector_type(8)));
typedef unsigned int u32x4 __attribute__((ext_vector_type(4)));
typedef float f32x4 __attribute__((ext_vector_type(4)));

struct cplx { float x, y; };

#define L_SEQ 2048
#define HID 512
#define NST 64

// ---------------- device scratch (fully rewritten every call) ----------------
__device__ __align__(16) cplx g_S[10][NST * NST];   // S[j] = Ab^(2^j), j=0..9
__device__ __align__(16) cplx g_ST[4][NST * NST];   // g_ST[j] = S[6+j]^T (R^{2^j})^T, R=Ab^64
__device__ __align__(16) cplx g_Bb[NST];
__device__ __align__(16) cplx g_c[NST];             // conj(C)
__device__ __align__(16) cplx g_V[64][NST];         // V_b = Ab^b Bb
__device__ __align__(16) cplx g_U[32][NST];         // U_a = (R^a)^T Cb
__device__ __align__(16) float g_k[L_SEQ];
__device__ __align__(16) u16 g_T[L_SEQ * L_SEQ];    // bf16 Toeplitz [i][j] = k[i-j]
__device__ __align__(16) u16 g_Xt[HID * L_SEQ];     // bf16 X^T  [h][l]
__device__ __align__(16) u16 g_W1[HID * HID];       // bf16 [n][k]
__device__ __align__(16) u16 g_W2[HID * HID];
__device__ __align__(16) u16 g_H[L_SEQ * HID];      // bf16 gelu(conv out) [l][h]

__device__ __forceinline__ cplx cmul(cplx a, cplx b) {
    return { a.x * b.x - a.y * b.y, a.x * b.y + a.y * b.x };
}
__device__ __forceinline__ cplx cmadd(cplx s, cplx a, cplx b) {
    s.x += a.x * b.x - a.y * b.y;
    s.y += a.x * b.y + a.y * b.x;
    return s;
}
__device__ __forceinline__ u16 f2bf(float f) {
    union { __hip_bfloat16 h; u16 u; } cv;
    cv.h = __float2bfloat16(f);
    return cv.u;
}

// ---------------- setup + Ab = A1@A0 (prep folded into every block) ----------------
__global__ __launch_bounds__(256) void square0(
    const float* lre, const float* lim, const float* pre, const float* pim,
    const float* bre, const float* bim, const float* cre, const float* cim,
    const float* lstep) {
    __shared__ cplx lam[NST], P[NST], Bv[NST], dd[NST];
    __shared__ cplx s2inv, S3;
    __shared__ float twodt;
    __shared__ cplx A0s[NST][NST + 2];
    __shared__ cplx A1s[4][NST];
    int tid = threadIdx.x;
    if (tid < NST) {
        lam[tid] = { lre[tid], lim[tid] };
        P[tid] = { pre[tid], pim[tid] };
        Bv[tid] = { bre[tid], bim[tid] };
    }
    if (tid == 0) twodt = 2.0f / expf(lstep[0]);
    __syncthreads();
    if (tid < NST) {
        cplx w = { twodt - lam[tid].x, -lam[tid].y };
        float den = w.x * w.x + w.y * w.y;
        dd[tid] = { w.x / den, -w.y / den };
    }
    __syncthreads();
    if (tid == 0) {
        cplx s = { 1.f, 0.f };
        cplx s3 = { 0.f, 0.f };
        for (int n = 0; n < NST; n++) {
            float pp = P[n].x * P[n].x + P[n].y * P[n].y;
            s.x += dd[n].x * pp;
            s.y += dd[n].y * pp;
            cplx pc = { P[n].x, -P[n].y };
            s3 = cmadd(s3, pc, cmul(dd[n], Bv[n]));
        }
        float den = s.x * s.x + s.y * s.y;
        s2inv = { s.x / den, -s.y / den };
        S3 = s3;
    }
    __syncthreads();
    for (int o = tid; o < NST * NST; o += 256) {
        int r = o >> 6, c = o & 63;
        cplx pc_conj = { P[c].x, -P[c].y };
        cplx a0 = cmul(P[r], pc_conj);
        a0 = { -a0.x, -a0.y };
        if (r == c) { a0.x += twodt + lam[r].x; a0.y += lam[r].y; }
        A0s[r][c] = a0;
    }
    int rbase = blockIdx.x * 4;
    {
        int rr = tid >> 6, c = tid & 63;
        int r = rbase + rr;
        cplx pc_conj = { P[c].x, -P[c].y };
        cplx t1 = cmul(dd[r], P[r]);
        t1 = cmul(t1, pc_conj);
        t1 = cmul(t1, dd[c]);
        t1 = cmul(t1, s2inv);
        cplx a1 = { -t1.x, -t1.y };
        if (r == c) { a1.x += dd[r].x; a1.y += dd[r].y; }
        A1s[rr][c] = a1;
    }
    if (blockIdx.x == 0 && tid < NST) {
        cplx t = cmul(dd[tid], Bv[tid]);
        cplx u = cmul(cmul(dd[tid], P[tid]), cmul(s2inv, S3));
        g_Bb[tid] = { 2.f * (t.x - u.x), 2.f * (t.y - u.y) };
        g_c[tid] = { cre[tid], -cim[tid] };
    }
    __syncthreads();
    int rr = tid >> 6, c = tid & 63;
    cplx acc = { 0.f, 0.f };
#pragma unroll 8
    for (int k = 0; k < NST; k++) acc = cmadd(acc, A1s[rr][k], A0s[k][c]);
    g_S[0][(rbase + rr) * NST + c] = acc;
}

// ---------------- S[jd] = S[js]^2 ; also store transpose for jd>=6 ----------------
__global__ __launch_bounds__(256) void square_step(int js, int jd) {
    const cplx* A = g_S[js];
    int gid = blockIdx.x * 256 + threadIdx.x;  // 4096
    int r = gid >> 6, c = gid & 63;
    cplx acc = { 0.f, 0.f };
#pragma unroll 8
    for (int k = 0; k < NST; k++) acc = cmadd(acc, A[r * NST + k], A[k * NST + c]);
    g_S[jd][gid] = acc;
    if (jd >= 6) g_ST[jd - 6][c * NST + r] = acc;  // transpose copy for U-chains
}

// ---------------- uv_convert: per-vector chains + X/W converts ----------------
// blocks 0..63: V_b ; 64..95: U_a ; 96..351: X->Xt ; 352..863: W1/W2
__global__ __launch_bounds__(256) void uv_convert(const float* x, const float* w1,
                                                  const float* w2) {
    __shared__ __align__(16) cplx vbuf[2][NST];
    __shared__ float tile[64][65];
    int b = blockIdx.x, tid = threadIdx.x;
    if (b < 96) {
        bool isV = b < 64;
        int idx = isV ? b : (b - 64);
        if (tid < NST) vbuf[0][tid] = isV ? g_Bb[tid] : g_c[tid];
        __syncthreads();
        int r = tid >> 2, kl = tid & 3;
        int s = 0;
        // helper lambda-free matvec macro: v_new = M @ vbuf[s]
#define MATVEC(Mptr)                                                            \
        {                                                                       \
            const cplx* M_ = (Mptr);                                            \
            float ax = 0.f, ay = 0.f;                                           \
            _Pragma("unroll")                                                   \
            for (int ip = 0; ip < 8; ip++) {                                    \
                int ke = ((ip + 2 * kl) & 7) * 2;                               \
                int k = kl * 16 + ke;                                           \
                f32x4 mv = *(const f32x4*)&M_[r * NST + k];                     \
                f32x4 vv = *(const f32x4*)&vbuf[s][k];                          \
                ax += mv.x * vv.x - mv.y * vv.y + mv.z * vv.z - mv.w * vv.w;    \
                ay += mv.x * vv.y + mv.y * vv.x + mv.z * vv.w + mv.w * vv.z;    \
            }                                                                   \
            ax += __shfl_xor(ax, 1); ay += __shfl_xor(ay, 1);                   \
            ax += __shfl_xor(ax, 2); ay += __shfl_xor(ay, 2);                   \
            if (kl == 0) { vbuf[s ^ 1][r].x = ax; vbuf[s ^ 1][r].y = ay; }      \
            __syncthreads();                                                    \
            s ^= 1;                                                             \
        }
        if (!isV) {
            // Cb = conjC + (Ab^2048)^T conjC ; Ab^2048 = S[9]^4 -> apply ST[3] 4x
            MATVEC(g_ST[3]); MATVEC(g_ST[3]); MATVEC(g_ST[3]); MATVEC(g_ST[3]);
            if (tid < NST) {
                vbuf[s][tid].x += g_c[tid].x;
                vbuf[s][tid].y += g_c[tid].y;
            }
            __syncthreads();
        }
        for (int j = 0; j < 6; j++) {
            if (!isV && j == 5) break;       // U index < 32: bits 0..4
            if (!((idx >> j) & 1)) continue;
            if (isV) {
                MATVEC(g_S[j]);
            } else if (j == 4) {             // R^16 = (R^8)^2 -> ST[3] twice
                MATVEC(g_ST[3]); MATVEC(g_ST[3]);
            } else {
                MATVEC(g_ST[j]);
            }
        }
#undef MATVEC
        if (tid < NST) {
            if (isV) g_V[idx][tid] = vbuf[s][tid];
            else     g_U[idx][tid] = vbuf[s][tid];
        }
    } else if (b < 352) {
        // X -> bf16 X^T
        int bb = b - 96;
        int lt = bb >> 3, ht = bb & 7;
#pragma unroll
        for (int i = 0; i < 16; i++) {
            int idx = i * 256 + tid;
            int rr = idx >> 6, cc = idx & 63;
            tile[rr][cc] = x[(lt * 64 + rr) * HID + ht * 64 + cc];
        }
        __syncthreads();
#pragma unroll
        for (int i = 0; i < 16; i++) {
            int idx = i * 256 + tid;
            int rr = idx >> 6, cc = idx & 63;
            g_Xt[(ht * 64 + rr) * L_SEQ + lt * 64 + cc] = f2bf(tile[cc][rr]);
        }
    } else {
        // W1/W2 -> bf16
        int t = (b - 352) * 256 + tid;  // 131072
        const float* src = (t < 65536) ? w1 : w2;
        u16* dst = (t < 65536) ? g_W1 : g_W2;
        int idx = (t < 65536) ? t : (t - 65536);
        float4 v = ((const float4*)src)[idx];
        unsigned long long pk = (unsigned long long)f2bf(v.x) |
                                ((unsigned long long)f2bf(v.y) << 16) |
                                ((unsigned long long)f2bf(v.z) << 32) |
                                ((unsigned long long)f2bf(v.w) << 48);
        ((unsigned long long*)dst)[idx] = pk;
    }
}

// ---------------- k[64a+b] = Re(U[a] . V[b]) ----------------
__global__ __launch_bounds__(256) void k_assemble() {
    int a = blockIdx.x, tid = threadIdx.x;
    int bq = tid >> 2, kl = tid & 3;
    float kr = 0.f;
#pragma unroll
    for (int ip = 0; ip < 8; ip++) {
        int k = kl * 16 + ip * 2;
        f32x4 uv = *(const f32x4*)&g_U[a][k];
        f32x4 vv = *(const f32x4*)&g_V[bq][k];
        kr += uv.x * vv.x - uv.y * vv.y + uv.z * vv.z - uv.w * vv.w;
    }
    kr += __shfl_xor(kr, 1);
    kr += __shfl_xor(kr, 2);
    if (kl == 0) g_k[a * 64 + bq] = kr;
}

// ---------------- Toeplitz build ----------------
__global__ __launch_bounds__(256) void build_T() {
    int gid = blockIdx.x * 256 + threadIdx.x;  // 524288
    int o = gid * 8;
    int i = o >> 11, j0 = o & 2047;
    u16x8 v;
#pragma unroll
    for (int q = 0; q < 8; q++) {
        int d = i - (j0 + q);
        v[q] = f2bf((d >= 0) ? g_k[d] : 0.f);
    }
    *(u16x8*)&g_T[o] = v;
}

// ---------------- conv GEMM: Y = T @ X (triangular), gelu -> H ----------------
__global__ __launch_bounds__(256) void conv_gemm() {
    __shared__ __align__(16) u16 As[64 * 64];
    __shared__ __align__(16) u16 Bs[64 * 64];
    int tid = threadIdx.x, l = tid & 63, w = tid >> 6;
    int wm = w >> 1, wn = w & 1;
    int bm = blockIdx.x >> 3, bn = blockIdx.x & 7;  // 32 x 8
    f32x4 acc[2][2] = {};
    int nkb = bm + 1;  // triangular
    int row0 = tid >> 3, kc0 = tid & 7;
    int row1 = (256 + tid) >> 3, kc1 = tid & 7;
    const u16* arow0 = &g_T[(bm * 64 + row0) * L_SEQ + kc0 * 8];
    const u16* arow1 = &g_T[(bm * 64 + row1) * L_SEQ + kc1 * 8];
    const u16* brow0 = &g_Xt[(bn * 64 + row0) * L_SEQ + kc0 * 8];
    const u16* brow1 = &g_Xt[(bn * 64 + row1) * L_SEQ + kc1 * 8];
    int sa0 = row0 * 8 + (kc0 ^ (row0 & 7));
    int sa1 = row1 * 8 + (kc1 ^ (row1 & 7));
    u32x4 ra0 = *(const u32x4*)arow0;
    u32x4 ra1 = *(const u32x4*)arow1;
    u32x4 rb0 = *(const u32x4*)brow0;
    u32x4 rb1 = *(const u32x4*)brow1;
    for (int kb = 0; kb < nkb; kb++) {
        __syncthreads();  // prior compute done reading As/Bs
        ((u32x4*)As)[sa0] = ra0;
        ((u32x4*)As)[sa1] = ra1;
        ((u32x4*)Bs)[sa0] = rb0;
        ((u32x4*)Bs)[sa1] = rb1;
        if (kb + 1 < nkb) {
            int k0 = (kb + 1) * 64;
            ra0 = *(const u32x4*)(arow0 + k0);
            ra1 = *(const u32x4*)(arow1 + k0);
            rb0 = *(const u32x4*)(brow0 + k0);
            rb1 = *(const u32x4*)(brow1 + k0);
        }
        __syncthreads();  // staging visible
#pragma unroll
        for (int ks = 0; ks < 2; ks++) {
            s16x8 af[2], bf[2];
#pragma unroll
            for (int m = 0; m < 2; m++) {
                int row = wm * 32 + m * 16 + (l & 15);
                int chunk = (ks * 4 + (l >> 4)) ^ (row & 7);
                af[m] = *(const s16x8*)&As[row * 64 + chunk * 8];
            }
#pragma unroll
            for (int n = 0; n < 2; n++) {
                int col = wn * 32 + n * 16 + (l & 15);
                int chunk = (ks * 4 + (l >> 4)) ^ (col & 7);
                bf[n] = *(const s16x8*)&Bs[col * 64 + chunk * 8];
            }
#pragma unroll
            for (int m = 0; m < 2; m++)
#pragma unroll
                for (int n = 0; n < 2; n++)
                    acc[m][n] = __builtin_amdgcn_mfma_f32_16x16x32_bf16(af[m], bf[n], acc[m][n], 0, 0, 0);
        }
    }
#pragma unroll
    for (int m = 0; m < 2; m++)
#pragma unroll
        for (int n = 0; n < 2; n++)
#pragma unroll
            for (int r4 = 0; r4 < 4; r4++) {
                int row = bm * 64 + wm * 32 + m * 16 + (l >> 4) * 4 + r4;
                int col = bn * 64 + wn * 32 + n * 16 + (l & 15);
                float y = acc[m][n][r4];
                float u = 1.5957691216057308f * (y + 0.044715f * y * y * y);
                float th = 1.f - 2.f / (__expf(u) + 1.f);
                g_H[row * HID + col] = f2bf(0.5f * y * (1.f + th));
            }
}

// ---------------- FFN: out = x + (H@W1^T + b1) * sigmoid(H@W2^T + b2) ----------------
__global__ __launch_bounds__(256) void ffn_gemm(const float* x, const float* b1,
                                                const float* b2, float* out) {
    __shared__ __align__(16) u16 As[64 * 64];
    __shared__ __align__(16) u16 B1s[64 * 64];
    __shared__ __align__(16) u16 B2s[64 * 64];
    int tid = threadIdx.x, l = tid & 63, w = tid >> 6;
    int wm = w >> 1, wn = w & 1;
    int bm = blockIdx.x >> 3, bn = blockIdx.x & 7;  // 32 x 8
    f32x4 acc1[2][2] = {}, acc2[2][2] = {};
    int row0 = tid >> 3, kc0 = tid & 7;
    int row1 = (256 + tid) >> 3;
    const u16* arow0 = &g_H[(bm * 64 + row0) * HID + kc0 * 8];
    const u16* arow1 = &g_H[(bm * 64 + row1) * HID + kc0 * 8];
    const u16* b1row0 = &g_W1[(bn * 64 + row0) * HID + kc0 * 8];
    const u16* b1row1 = &g_W1[(bn * 64 + row1) * HID + kc0 * 8];
    const u16* b2row0 = &g_W2[(bn * 64 + row0) * HID + kc0 * 8];
    const u16* b2row1 = &g_W2[(bn * 64 + row1) * HID + kc0 * 8];
    int sa0 = row0 * 8 + (kc0 ^ (row0 & 7));
    int sa1 = row1 * 8 + (kc0 ^ (row1 & 7));
    u32x4 ra0 = *(const u32x4*)arow0;
    u32x4 ra1 = *(const u32x4*)arow1;
    u32x4 rb10 = *(const u32x4*)b1row0;
    u32x4 rb11 = *(const u32x4*)b1row1;
    u32x4 rb20 = *(const u32x4*)b2row0;
    u32x4 rb21 = *(const u32x4*)b2row1;
    for (int kb = 0; kb < 8; kb++) {
        __syncthreads();
        ((u32x4*)As)[sa0] = ra0;
        ((u32x4*)As)[sa1] = ra1;
        ((u32x4*)B1s)[sa0] = rb10;
        ((u32x4*)B1s)[sa1] = rb11;
        ((u32x4*)B2s)[sa0] = rb20;
        ((u32x4*)B2s)[sa1] = rb21;
        if (kb < 7) {
            int k0 = (kb + 1) * 64;
            ra0 = *(const u32x4*)(arow0 + k0);
            ra1 = *(const u32x4*)(arow1 + k0);
            rb10 = *(const u32x4*)(b1row0 + k0);
            rb11 = *(const u32x4*)(b1row1 + k0);
            rb20 = *(const u32x4*)(b2row0 + k0);
            rb21 = *(const u32x4*)(b2row1 + k0);
        }
        __syncthreads();
#pragma unroll
        for (int ks = 0; ks < 2; ks++) {
            s16x8 af[2], b1f[2], b2f[2];
#pragma unroll
            for (int m = 0; m < 2; m++) {
                int row = wm * 32 + m * 16 + (l & 15);
                int chunk = (ks * 4 + (l >> 4)) ^ (row & 7);
                af[m] = *(const s16x8*)&As[row * 64 + chunk * 8];
            }
#pragma unroll
            for (int n = 0; n < 2; n++) {
                int col = wn * 32 + n * 16 + (l & 15);
                int chunk = (ks * 4 + (l >> 4)) ^ (col & 7);
                b1f[n] = *(const s16x8*)&B1s[col * 64 + chunk * 8];
                b2f[n] = *(const s16x8*)&B2s[col * 64 + chunk * 8];
            }
#pragma unroll
            for (int m = 0; m < 2; m++)
#pragma unroll
                for (int n = 0; n < 2; n++) {
                    acc1[m][n] = __builtin_amdgcn_mfma_f32_16x16x32_bf16(af[m], b1f[n], acc1[m][n], 0, 0, 0);
                    acc2[m][n] = __builtin_amdgcn_mfma_f32_16x16x32_bf16(af[m], b2f[n], acc2[m][n], 0, 0, 0);
                }
        }
    }
#pragma unroll
    for (int m = 0; m < 2; m++)
#pragma unroll
        for (int n = 0; n < 2; n++)
#pragma unroll
            for (int r4 = 0; r4 < 4; r4++) {
                int row = bm * 64 + wm * 32 + m * 16 + (l >> 4) * 4 + r4;
                int col = bn * 64 + wn * 32 + n * 16 + (l & 15);
                float g1 = acc1[m][n][r4] + b1[col];
                float g2 = acc2[m][n][r4] + b2[col];
                float sg = 1.f / (1.f + __expf(-g2));
                out[row * HID + col] = x[row * HID + col] + g1 * sg;
            }
}

extern "C" void kernel_launch(void* const* d_in, const int* in_sizes, int n_in,
                              void* d_out, int out_size, void* d_ws, size_t ws_size,
                              hipStream_t stream) {
    const float* x = (const float*)d_in[0];
    const float* lre = (const float*)d_in[1];
    const float* lim = (const float*)d_in[2];
    const float* pre = (const float*)d_in[3];
    const float* pim = (const float*)d_in[4];
    const float* bre = (const float*)d_in[5];
    const float* bim = (const float*)d_in[6];
    const float* cre = (const float*)d_in[7];
    const float* cim = (const float*)d_in[8];
    const float* lstep = (const float*)d_in[9];
    const float* w1 = (const float*)d_in[10];
    const float* b1 = (const float*)d_in[11];
    const float* w2 = (const float*)d_in[12];
    const float* b2 = (const float*)d_in[13];
    float* out = (float*)d_out;

    square0<<<16, 256, 0, stream>>>(lre, lim, pre, pim, bre, bim, cre, cim, lstep);
    for (int j = 1; j <= 9; j++)
        square_step<<<16, 256, 0, stream>>>(j - 1, j);  // S[j] = Ab^(2^j), ST for j>=6
    uv_convert<<<864, 256, 0, stream>>>(x, w1, w2);
    k_assemble<<<32, 256, 0, stream>>>();
    build_T<<<2048, 256, 0, stream>>>();
    conv_gemm<<<256, 256, 0, stream>>>();
    ffn_gemm<<<256, 256, 0, stream>>>(x, b1, b2, out);
}

// Round 4
// 100.377 us; speedup vs baseline: 3.6205x; 1.0660x over previous
//
#include <hip/hip_runtime.h>
#include <hip/hip_bf16.h>

typedef unsigned short u16;
typedef short s16x8 __attribute__((ext_vector_type(8)));
typedef u16 u16x8 __attribute__((ext_vector_type(8)));
typedef unsigned int u32x4 __attribute__((ext_vector_type(4)));
typedef float f32x4 __attribute__((ext_vector_type(4)));

struct cplx { float x, y; };

#define L_SEQ 2048
#define HID 512
#define NST 64

// ---------------- device scratch (fully rewritten every call) ----------------
__device__ __align__(16) cplx g_khat[L_SEQ];        // k̂_j at 2048 roots of unity
__device__ __align__(16) float g_k[L_SEQ];
__device__ __align__(16) u16 g_T[L_SEQ * L_SEQ];    // bf16 Toeplitz [i][j] = k[i-j]
__device__ __align__(16) u16 g_Xt[HID * L_SEQ];     // bf16 X^T  [h][l]
__device__ __align__(16) u16 g_W1[HID * HID];       // bf16 [n][k]
__device__ __align__(16) u16 g_W2[HID * HID];
__device__ __align__(16) u16 g_H[L_SEQ * HID];      // bf16 gelu(conv out) [l][h]

__device__ __forceinline__ cplx cmul(cplx a, cplx b) {
    return { a.x * b.x - a.y * b.y, a.x * b.y + a.y * b.x };
}
__device__ __forceinline__ u16 f2bf(float f) {
    union { __hip_bfloat16 h; u16 u; } cv;
    cv.h = __float2bfloat16(f);
    return cv.u;
}

// ---------------- k̂_j = 2 conj(C)^T [ (2/Δ)(1-ω)I - (1+ω)A ]^{-1} B ----------------
// A = diag(Λ) - P P^H ; Woodbury -> 4 Cauchy sums of length 64 per frequency.
__global__ __launch_bounds__(256) void khat_kernel(
    const float* lre, const float* lim, const float* pre, const float* pim,
    const float* bre, const float* bim, const float* cre, const float* cim,
    const float* lstep) {
    __shared__ float sLre[NST], sLim[NST], sPre[NST], sPim[NST];
    __shared__ float sBre[NST], sBim[NST], sCre[NST], sCim[NST];
    int tid = threadIdx.x;
    if (tid < NST) {
        sLre[tid] = lre[tid]; sLim[tid] = lim[tid];
        sPre[tid] = pre[tid]; sPim[tid] = pim[tid];
        sBre[tid] = bre[tid]; sBim[tid] = bim[tid];
        sCre[tid] = cre[tid]; sCim[tid] = cim[tid];
    }
    __syncthreads();
    int j = blockIdx.x * 256 + tid;  // 0..2047
    float tdt = 2.0f * __expf(-lstep[0]);          // 2/step
    float th = 0.00306796157577128245f * j;        // 2*pi/2048 * j
    float sn, cs;
    __sincosf(th, &sn, &cs);
    // omega = e^{-i th} = (cs, -sn)
    float aRe = tdt * (1.f - cs), aIm = tdt * sn;  // (2/dt)(1-w)
    float bRe = 1.f + cs, bIm = -sn;               // beta = 1+w
    float cBx = 0.f, cBy = 0.f, cPx = 0.f, cPy = 0.f;
    float pBx = 0.f, pBy = 0.f, pPx = 0.f, pPy = 0.f;
#pragma unroll 8
    for (int n = 0; n < NST; n++) {
        // D_n = a - beta*Lam_n
        float Lre = sLre[n], Lim = sLim[n];
        float Dre = aRe - (bRe * Lre - bIm * Lim);
        float Dim = aIm - (bRe * Lim + bIm * Lre);
        float inv = 1.f / (Dre * Dre + Dim * Dim);
        float eRe = Dre * inv, eIm = -Dim * inv;   // 1/D_n
        // t1 = conj(C)_n / D_n
        float cRe = sCre[n], cIm = -sCim[n];
        float t1Re = cRe * eRe - cIm * eIm, t1Im = cRe * eIm + cIm * eRe;
        // t2 = conj(P)_n / D_n
        float qRe = sPre[n], qIm = -sPim[n];
        float t2Re = qRe * eRe - qIm * eIm, t2Im = qRe * eIm + qIm * eRe;
        float BRe = sBre[n], BIm = sBim[n], PRe = sPre[n], PIm = sPim[n];
        cBx += t1Re * BRe - t1Im * BIm; cBy += t1Re * BIm + t1Im * BRe;
        cPx += t1Re * PRe - t1Im * PIm; cPy += t1Re * PIm + t1Im * PRe;
        pBx += t2Re * BRe - t2Im * BIm; pBy += t2Re * BIm + t2Im * BRe;
        pPx += t2Re * PRe - t2Im * PIm; pPy += t2Re * PIm + t2Im * PRe;
    }
    // corr = beta*cP*pB / (1 + beta*pP)
    float denx = 1.f + (bRe * pPx - bIm * pPy);
    float deny = (bRe * pPy + bIm * pPx);
    float bcPx = bRe * cPx - bIm * cPy;
    float bcPy = bRe * cPy + bIm * cPx;
    float numx = bcPx * pBx - bcPy * pBy;
    float numy = bcPx * pBy + bcPy * pBx;
    float dinv = 1.f / (denx * denx + deny * deny);
    float corx = (numx * denx + numy * deny) * dinv;
    float cory = (numy * denx - numx * deny) * dinv;
    g_khat[j] = { 2.f * (cBx - corx), 2.f * (cBy - cory) };
}

// ---------------- Re(k_t) via Hermitian-symmetrized direct IDFT ----------------
// m̂_j = (k̂_j + conj(k̂_{L-j}))/2  (k complex -> only its real part feeds T)
__global__ __launch_bounds__(128) void k_ifft() {
    __shared__ float csv[2048], snv[2048];
    __shared__ float reh[1025], imh[1025];
    int tid = threadIdx.x;
    for (int m = tid; m < 2048; m += 128) {
        float s, c;
        __sincosf(0.00306796157577128245f * m, &s, &c);
        csv[m] = c;
        snv[m] = s;
    }
    for (int m = tid; m <= 1024; m += 128) {
        int mir = (2048 - m) & 2047;
        cplx a = g_khat[m], b = g_khat[mir];
        reh[m] = 0.5f * (a.x + b.x);
        imh[m] = 0.5f * (a.y - b.y);
    }
    __syncthreads();
    int t = blockIdx.x * 128 + tid;
    float acc = reh[0] + (1 - 2 * (t & 1)) * reh[1024];
    int idx = t & 2047;
    int step = t & 2047;
#pragma unroll 8
    for (int j = 1; j < 1024; j++) {
        acc += 2.f * (reh[j] * csv[idx] - imh[j] * snv[idx]);
        idx = (idx + step) & 2047;
    }
    g_k[t] = acc * (1.f / 2048.f);
}

// ---------------- fused conversions + Toeplitz build ----------------
// blocks 0..255: X -> bf16 X^T ; 256..767: W1/W2 -> bf16 ; 768..2815: build T
__global__ __launch_bounds__(256) void fused_convert(const float* x, const float* w1,
                                                     const float* w2) {
    __shared__ float tile[64][65];
    int b = blockIdx.x, tid = threadIdx.x;
    if (b < 256) {
        int lt = b >> 3, ht = b & 7;
#pragma unroll
        for (int i = 0; i < 16; i++) {
            int idx = i * 256 + tid;
            int rr = idx >> 6, cc = idx & 63;
            tile[rr][cc] = x[(lt * 64 + rr) * HID + ht * 64 + cc];
        }
        __syncthreads();
#pragma unroll
        for (int i = 0; i < 16; i++) {
            int idx = i * 256 + tid;
            int rr = idx >> 6, cc = idx & 63;
            g_Xt[(ht * 64 + rr) * L_SEQ + lt * 64 + cc] = f2bf(tile[cc][rr]);
        }
    } else if (b < 768) {
        int t = (b - 256) * 256 + tid;  // 131072
        const float* src = (t < 65536) ? w1 : w2;
        u16* dst = (t < 65536) ? g_W1 : g_W2;
        int idx = (t < 65536) ? t : (t - 65536);
        float4 v = ((const float4*)src)[idx];
        unsigned long long pk = (unsigned long long)f2bf(v.x) |
                                ((unsigned long long)f2bf(v.y) << 16) |
                                ((unsigned long long)f2bf(v.z) << 32) |
                                ((unsigned long long)f2bf(v.w) << 48);
        ((unsigned long long*)dst)[idx] = pk;
    } else {
        int gid = (b - 768) * 256 + tid;  // 524288
        int o = gid * 8;
        int i = o >> 11, j0 = o & 2047;
        u16x8 v;
#pragma unroll
        for (int q = 0; q < 8; q++) {
            int d = i - (j0 + q);
            v[q] = f2bf((d >= 0) ? g_k[d] : 0.f);
        }
        *(u16x8*)&g_T[o] = v;
    }
}

// ---------------- conv GEMM: Y = T @ X (triangular), gelu -> H ----------------
__global__ __launch_bounds__(256) void conv_gemm() {
    __shared__ __align__(16) u16 As[64 * 64];
    __shared__ __align__(16) u16 Bs[64 * 64];
    int tid = threadIdx.x, l = tid & 63, w = tid >> 6;
    int wm = w >> 1, wn = w & 1;
    int bm = blockIdx.x >> 3, bn = blockIdx.x & 7;  // 32 x 8
    f32x4 acc[2][2] = {};
    int nkb = bm + 1;  // triangular
    int row0 = tid >> 3, kc0 = tid & 7;
    int row1 = (256 + tid) >> 3, kc1 = tid & 7;
    const u16* arow0 = &g_T[(bm * 64 + row0) * L_SEQ + kc0 * 8];
    const u16* arow1 = &g_T[(bm * 64 + row1) * L_SEQ + kc1 * 8];
    const u16* brow0 = &g_Xt[(bn * 64 + row0) * L_SEQ + kc0 * 8];
    const u16* brow1 = &g_Xt[(bn * 64 + row1) * L_SEQ + kc1 * 8];
    int sa0 = row0 * 8 + (kc0 ^ (row0 & 7));
    int sa1 = row1 * 8 + (kc1 ^ (row1 & 7));
    u32x4 ra0 = *(const u32x4*)arow0;
    u32x4 ra1 = *(const u32x4*)arow1;
    u32x4 rb0 = *(const u32x4*)brow0;
    u32x4 rb1 = *(const u32x4*)brow1;
    for (int kb = 0; kb < nkb; kb++) {
        __syncthreads();  // prior compute done reading As/Bs
        ((u32x4*)As)[sa0] = ra0;
        ((u32x4*)As)[sa1] = ra1;
        ((u32x4*)Bs)[sa0] = rb0;
        ((u32x4*)Bs)[sa1] = rb1;
        if (kb + 1 < nkb) {
            int k0 = (kb + 1) * 64;
            ra0 = *(const u32x4*)(arow0 + k0);
            ra1 = *(const u32x4*)(arow1 + k0);
            rb0 = *(const u32x4*)(brow0 + k0);
            rb1 = *(const u32x4*)(brow1 + k0);
        }
        __syncthreads();  // staging visible
#pragma unroll
        for (int ks = 0; ks < 2; ks++) {
            s16x8 af[2], bf[2];
#pragma unroll
            for (int m = 0; m < 2; m++) {
                int row = wm * 32 + m * 16 + (l & 15);
                int chunk = (ks * 4 + (l >> 4)) ^ (row & 7);
                af[m] = *(const s16x8*)&As[row * 64 + chunk * 8];
            }
#pragma unroll
            for (int n = 0; n < 2; n++) {
                int col = wn * 32 + n * 16 + (l & 15);
                int chunk = (ks * 4 + (l >> 4)) ^ (col & 7);
                bf[n] = *(const s16x8*)&Bs[col * 64 + chunk * 8];
            }
#pragma unroll
            for (int m = 0; m < 2; m++)
#pragma unroll
                for (int n = 0; n < 2; n++)
                    acc[m][n] = __builtin_amdgcn_mfma_f32_16x16x32_bf16(af[m], bf[n], acc[m][n], 0, 0, 0);
        }
    }
#pragma unroll
    for (int m = 0; m < 2; m++)
#pragma unroll
        for (int n = 0; n < 2; n++)
#pragma unroll
            for (int r4 = 0; r4 < 4; r4++) {
                int row = bm * 64 + wm * 32 + m * 16 + (l >> 4) * 4 + r4;
                int col = bn * 64 + wn * 32 + n * 16 + (l & 15);
                float y = acc[m][n][r4];
                float u = 1.5957691216057308f * (y + 0.044715f * y * y * y);
                float th = 1.f - 2.f / (__expf(u) + 1.f);
                g_H[row * HID + col] = f2bf(0.5f * y * (1.f + th));
            }
}

// ---------------- FFN: out = x + (H@W1^T + b1) * sigmoid(H@W2^T + b2) ----------------
__global__ __launch_bounds__(256) void ffn_gemm(const float* x, const float* b1,
                                                const float* b2, float* out) {
    __shared__ __align__(16) u16 As[64 * 64];
    __shared__ __align__(16) u16 B1s[64 * 64];
    __shared__ __align__(16) u16 B2s[64 * 64];
    int tid = threadIdx.x, l = tid & 63, w = tid >> 6;
    int wm = w >> 1, wn = w & 1;
    int bm = blockIdx.x >> 3, bn = blockIdx.x & 7;  // 32 x 8
    f32x4 acc1[2][2] = {}, acc2[2][2] = {};
    int row0 = tid >> 3, kc0 = tid & 7;
    int row1 = (256 + tid) >> 3;
    const u16* arow0 = &g_H[(bm * 64 + row0) * HID + kc0 * 8];
    const u16* arow1 = &g_H[(bm * 64 + row1) * HID + kc0 * 8];
    const u16* b1row0 = &g_W1[(bn * 64 + row0) * HID + kc0 * 8];
    const u16* b1row1 = &g_W1[(bn * 64 + row1) * HID + kc0 * 8];
    const u16* b2row0 = &g_W2[(bn * 64 + row0) * HID + kc0 * 8];
    const u16* b2row1 = &g_W2[(bn * 64 + row1) * HID + kc0 * 8];
    int sa0 = row0 * 8 + (kc0 ^ (row0 & 7));
    int sa1 = row1 * 8 + (kc0 ^ (row1 & 7));
    u32x4 ra0 = *(const u32x4*)arow0;
    u32x4 ra1 = *(const u32x4*)arow1;
    u32x4 rb10 = *(const u32x4*)b1row0;
    u32x4 rb11 = *(const u32x4*)b1row1;
    u32x4 rb20 = *(const u32x4*)b2row0;
    u32x4 rb21 = *(const u32x4*)b2row1;
    for (int kb = 0; kb < 8; kb++) {
        __syncthreads();
        ((u32x4*)As)[sa0] = ra0;
        ((u32x4*)As)[sa1] = ra1;
        ((u32x4*)B1s)[sa0] = rb10;
        ((u32x4*)B1s)[sa1] = rb11;
        ((u32x4*)B2s)[sa0] = rb20;
        ((u32x4*)B2s)[sa1] = rb21;
        if (kb < 7) {
            int k0 = (kb + 1) * 64;
            ra0 = *(const u32x4*)(arow0 + k0);
            ra1 = *(const u32x4*)(arow1 + k0);
            rb10 = *(const u32x4*)(b1row0 + k0);
            rb11 = *(const u32x4*)(b1row1 + k0);
            rb20 = *(const u32x4*)(b2row0 + k0);
            rb21 = *(const u32x4*)(b2row1 + k0);
        }
        __syncthreads();
#pragma unroll
        for (int ks = 0; ks < 2; ks++) {
            s16x8 af[2], b1f[2], b2f[2];
#pragma unroll
            for (int m = 0; m < 2; m++) {
                int row = wm * 32 + m * 16 + (l & 15);
                int chunk = (ks * 4 + (l >> 4)) ^ (row & 7);
                af[m] = *(const s16x8*)&As[row * 64 + chunk * 8];
            }
#pragma unroll
            for (int n = 0; n < 2; n++) {
                int col = wn * 32 + n * 16 + (l & 15);
                int chunk = (ks * 4 + (l >> 4)) ^ (col & 7);
                b1f[n] = *(const s16x8*)&B1s[col * 64 + chunk * 8];
                b2f[n] = *(const s16x8*)&B2s[col * 64 + chunk * 8];
            }
#pragma unroll
            for (int m = 0; m < 2; m++)
#pragma unroll
                for (int n = 0; n < 2; n++) {
                    acc1[m][n] = __builtin_amdgcn_mfma_f32_16x16x32_bf16(af[m], b1f[n], acc1[m][n], 0, 0, 0);
                    acc2[m][n] = __builtin_amdgcn_mfma_f32_16x16x32_bf16(af[m], b2f[n], acc2[m][n], 0, 0, 0);
                }
        }
    }
#pragma unroll
    for (int m = 0; m < 2; m++)
#pragma unroll
        for (int n = 0; n < 2; n++)
#pragma unroll
            for (int r4 = 0; r4 < 4; r4++) {
                int row = bm * 64 + wm * 32 + m * 16 + (l >> 4) * 4 + r4;
                int col = bn * 64 + wn * 32 + n * 16 + (l & 15);
                float g1 = acc1[m][n][r4] + b1[col];
                float g2 = acc2[m][n][r4] + b2[col];
                float sg = 1.f / (1.f + __expf(-g2));
                out[row * HID + col] = x[row * HID + col] + g1 * sg;
            }
}

extern "C" void kernel_launch(void* const* d_in, const int* in_sizes, int n_in,
                              void* d_out, int out_size, void* d_ws, size_t ws_size,
                              hipStream_t stream) {
    const float* x = (const float*)d_in[0];
    const float* lre = (const float*)d_in[1];
    const float* lim = (const float*)d_in[2];
    const float* pre = (const float*)d_in[3];
    const float* pim = (const float*)d_in[4];
    const float* bre = (const float*)d_in[5];
    const float* bim = (const float*)d_in[6];
    const float* cre = (const float*)d_in[7];
    const float* cim = (const float*)d_in[8];
    const float* lstep = (const float*)d_in[9];
    const float* w1 = (const float*)d_in[10];
    const float* b1 = (const float*)d_in[11];
    const float* w2 = (const float*)d_in[12];
    const float* b2 = (const float*)d_in[13];
    float* out = (float*)d_out;

    khat_kernel<<<8, 256, 0, stream>>>(lre, lim, pre, pim, bre, bim, cre, cim, lstep);
    k_ifft<<<16, 128, 0, stream>>>();
    fused_convert<<<2816, 256, 0, stream>>>(x, w1, w2);
    conv_gemm<<<256, 256, 0, stream>>>();
    ffn_gemm<<<256, 256, 0, stream>>>(x, b1, b2, out);
}

// Round 5
// 55.630 us; speedup vs baseline: 6.5327x; 1.8044x over previous
//
#include <hip/hip_runtime.h>
#include <hip/hip_bf16.h>

typedef unsigned short u16;
typedef short s16x8 __attribute__((ext_vector_type(8)));
typedef u16 u16x8 __attribute__((ext_vector_type(8)));
typedef unsigned int u32x4 __attribute__((ext_vector_type(4)));
typedef float f32x4 __attribute__((ext_vector_type(4)));

struct cplx { float x, y; };

#define L_SEQ 2048
#define HID 512
#define NST 64

// ---------------- device scratch (fully rewritten every call) ----------------
__device__ __align__(16) cplx g_khat[L_SEQ];        // k̂_j at 2048 roots of unity
__device__ __align__(16) float g_k[L_SEQ];
__device__ __align__(16) u16 g_T[L_SEQ * L_SEQ];    // bf16 Toeplitz [i][j] = k[i-j]
__device__ __align__(16) u16 g_Xt[HID * L_SEQ];     // bf16 X^T  [h][l]
__device__ __align__(16) u16 g_W1[HID * HID];       // bf16 [n][k]
__device__ __align__(16) u16 g_W2[HID * HID];
__device__ __align__(16) u16 g_H[L_SEQ * HID];      // bf16 gelu(conv out) [l][h]

__device__ __forceinline__ u16 f2bf(float f) {
    union { __hip_bfloat16 h; u16 u; } cv;
    cv.h = __float2bfloat16(f);
    return cv.u;
}

// ---------------- k̂_j = 2 conj(C)^T [ (2/Δ)(1-ω)I - (1+ω)A ]^{-1} B ----------------
// A = diag(Λ) - P P^H ; Woodbury -> 4 Cauchy sums of length 64 per frequency.
__global__ __launch_bounds__(256) void khat_kernel(
    const float* lre, const float* lim, const float* pre, const float* pim,
    const float* bre, const float* bim, const float* cre, const float* cim,
    const float* lstep) {
    __shared__ float sLre[NST], sLim[NST], sPre[NST], sPim[NST];
    __shared__ float sBre[NST], sBim[NST], sCre[NST], sCim[NST];
    int tid = threadIdx.x;
    if (tid < NST) {
        sLre[tid] = lre[tid]; sLim[tid] = lim[tid];
        sPre[tid] = pre[tid]; sPim[tid] = pim[tid];
        sBre[tid] = bre[tid]; sBim[tid] = bim[tid];
        sCre[tid] = cre[tid]; sCim[tid] = cim[tid];
    }
    __syncthreads();
    int j = blockIdx.x * 256 + tid;  // 0..2047
    float tdt = 2.0f * __expf(-lstep[0]);          // 2/step
    float th = 0.00306796157577128245f * j;        // 2*pi/2048 * j
    float sn, cs;
    __sincosf(th, &sn, &cs);
    // omega = e^{-i th} = (cs, -sn)
    float aRe = tdt * (1.f - cs), aIm = tdt * sn;  // (2/dt)(1-w)
    float bRe = 1.f + cs, bIm = -sn;               // beta = 1+w
    float cBx = 0.f, cBy = 0.f, cPx = 0.f, cPy = 0.f;
    float pBx = 0.f, pBy = 0.f, pPx = 0.f, pPy = 0.f;
#pragma unroll 8
    for (int n = 0; n < NST; n++) {
        // D_n = a - beta*Lam_n
        float Lre = sLre[n], Lim = sLim[n];
        float Dre = aRe - (bRe * Lre - bIm * Lim);
        float Dim = aIm - (bRe * Lim + bIm * Lre);
        float inv = 1.f / (Dre * Dre + Dim * Dim);
        float eRe = Dre * inv, eIm = -Dim * inv;   // 1/D_n
        // t1 = conj(C)_n / D_n
        float cRe = sCre[n], cIm = -sCim[n];
        float t1Re = cRe * eRe - cIm * eIm, t1Im = cRe * eIm + cIm * eRe;
        // t2 = conj(P)_n / D_n
        float qRe = sPre[n], qIm = -sPim[n];
        float t2Re = qRe * eRe - qIm * eIm, t2Im = qRe * eIm + qIm * eRe;
        float BRe = sBre[n], BIm = sBim[n], PRe = sPre[n], PIm = sPim[n];
        cBx += t1Re * BRe - t1Im * BIm; cBy += t1Re * BIm + t1Im * BRe;
        cPx += t1Re * PRe - t1Im * PIm; cPy += t1Re * PIm + t1Im * PRe;
        pBx += t2Re * BRe - t2Im * BIm; pBy += t2Re * BIm + t2Im * BRe;
        pPx += t2Re * PRe - t2Im * PIm; pPy += t2Re * PIm + t2Im * PRe;
    }
    // corr = beta*cP*pB / (1 + beta*pP)
    float denx = 1.f + (bRe * pPx - bIm * pPy);
    float deny = (bRe * pPy + bIm * pPx);
    float bcPx = bRe * cPx - bIm * cPy;
    float bcPy = bRe * cPy + bIm * cPx;
    float numx = bcPx * pBx - bcPy * pBy;
    float numy = bcPx * pBy + bcPy * pBx;
    float dinv = 1.f / (denx * denx + deny * deny);
    float corx = (numx * denx + numy * deny) * dinv;
    float cory = (numy * denx - numx * deny) * dinv;
    g_khat[j] = { 2.f * (cBx - corx), 2.f * (cBy - cory) };
}

// ---------------- Re(k_t) via Hermitian-symmetrized direct IDFT ----------------
// one wave per t; lane l sums j = l + 64*i, twiddles computed on the fly (no LDS)
__global__ __launch_bounds__(256) void k_ifft() {
    int tid = threadIdx.x;
    int l = tid & 63;
    int t = blockIdx.x * 4 + (tid >> 6);  // 512 blocks x 4 waves = 2048 t's
    float acc = 0.f;
#pragma unroll
    for (int i = 0; i < 16; i++) {
        int j = l + 64 * i;  // 0..1023
        cplx a = g_khat[j];
        cplx b = g_khat[(2048 - j) & 2047];
        float re = 0.5f * (a.x + b.x);        // m̂ real
        float im = 0.5f * (a.y - b.y);        // m̂ imag
        int idx = (j * t) & 2047;
        float s, c;
        __sincosf(0.00306796157577128245f * idx, &s, &c);
        float wgt = (j == 0) ? 1.f : 2.f;
        acc += wgt * (re * c - im * s);
    }
    if (l == 0) {
        // j = 1024 term: imh = 0, reh = khat[1024].x, weight (-1)^t
        acc += (1 - 2 * (t & 1)) * g_khat[1024].x;
    }
#pragma unroll
    for (int off = 1; off < 64; off <<= 1) acc += __shfl_xor(acc, off);
    if (l == 0) g_k[t] = acc * (1.f / 2048.f);
}

// ---------------- fused conversions + Toeplitz build ----------------
// blocks 0..255: X -> bf16 X^T ; 256..767: W1/W2 -> bf16 ; 768..2815: build T
__global__ __launch_bounds__(256) void fused_convert(const float* x, const float* w1,
                                                     const float* w2) {
    __shared__ float tile[64][65];
    int b = blockIdx.x, tid = threadIdx.x;
    if (b < 256) {
        int lt = b >> 3, ht = b & 7;
#pragma unroll
        for (int i = 0; i < 16; i++) {
            int idx = i * 256 + tid;
            int rr = idx >> 6, cc = idx & 63;
            tile[rr][cc] = x[(lt * 64 + rr) * HID + ht * 64 + cc];
        }
        __syncthreads();
#pragma unroll
        for (int i = 0; i < 16; i++) {
            int idx = i * 256 + tid;
            int rr = idx >> 6, cc = idx & 63;
            g_Xt[(ht * 64 + rr) * L_SEQ + lt * 64 + cc] = f2bf(tile[cc][rr]);
        }
    } else if (b < 768) {
        int t = (b - 256) * 256 + tid;  // 131072
        const float* src = (t < 65536) ? w1 : w2;
        u16* dst = (t < 65536) ? g_W1 : g_W2;
        int idx = (t < 65536) ? t : (t - 65536);
        float4 v = ((const float4*)src)[idx];
        unsigned long long pk = (unsigned long long)f2bf(v.x) |
                                ((unsigned long long)f2bf(v.y) << 16) |
                                ((unsigned long long)f2bf(v.z) << 32) |
                                ((unsigned long long)f2bf(v.w) << 48);
        ((unsigned long long*)dst)[idx] = pk;
    } else {
        int gid = (b - 768) * 256 + tid;  // 524288
        int o = gid * 8;
        int i = o >> 11, j0 = o & 2047;
        u16x8 v;
#pragma unroll
        for (int q = 0; q < 8; q++) {
            int d = i - (j0 + q);
            v[q] = f2bf((d >= 0) ? g_k[d] : 0.f);
        }
        *(u16x8*)&g_T[o] = v;
    }
}

// ---------------- conv GEMM: Y = T @ X (triangular), gelu -> H ----------------
__global__ __launch_bounds__(256) void conv_gemm() {
    __shared__ __align__(16) u16 As[64 * 64];
    __shared__ __align__(16) u16 Bs[64 * 64];
    int tid = threadIdx.x, l = tid & 63, w = tid >> 6;
    int wm = w >> 1, wn = w & 1;
    int bm = blockIdx.x >> 3, bn = blockIdx.x & 7;  // 32 x 8
    f32x4 acc[2][2] = {};
    int nkb = bm + 1;  // triangular
    int row0 = tid >> 3, kc0 = tid & 7;
    int row1 = (256 + tid) >> 3, kc1 = tid & 7;
    const u16* arow0 = &g_T[(bm * 64 + row0) * L_SEQ + kc0 * 8];
    const u16* arow1 = &g_T[(bm * 64 + row1) * L_SEQ + kc1 * 8];
    const u16* brow0 = &g_Xt[(bn * 64 + row0) * L_SEQ + kc0 * 8];
    const u16* brow1 = &g_Xt[(bn * 64 + row1) * L_SEQ + kc1 * 8];
    int sa0 = row0 * 8 + (kc0 ^ (row0 & 7));
    int sa1 = row1 * 8 + (kc1 ^ (row1 & 7));
    u32x4 ra0 = *(const u32x4*)arow0;
    u32x4 ra1 = *(const u32x4*)arow1;
    u32x4 rb0 = *(const u32x4*)brow0;
    u32x4 rb1 = *(const u32x4*)brow1;
    for (int kb = 0; kb < nkb; kb++) {
        __syncthreads();  // prior compute done reading As/Bs
        ((u32x4*)As)[sa0] = ra0;
        ((u32x4*)As)[sa1] = ra1;
        ((u32x4*)Bs)[sa0] = rb0;
        ((u32x4*)Bs)[sa1] = rb1;
        if (kb + 1 < nkb) {
            int k0 = (kb + 1) * 64;
            ra0 = *(const u32x4*)(arow0 + k0);
            ra1 = *(const u32x4*)(arow1 + k0);
            rb0 = *(const u32x4*)(brow0 + k0);
            rb1 = *(const u32x4*)(brow1 + k0);
        }
        __syncthreads();  // staging visible
#pragma unroll
        for (int ks = 0; ks < 2; ks++) {
            s16x8 af[2], bf[2];
#pragma unroll
            for (int m = 0; m < 2; m++) {
                int row = wm * 32 + m * 16 + (l & 15);
                int chunk = (ks * 4 + (l >> 4)) ^ (row & 7);
                af[m] = *(const s16x8*)&As[row * 64 + chunk * 8];
            }
#pragma unroll
            for (int n = 0; n < 2; n++) {
                int col = wn * 32 + n * 16 + (l & 15);
                int chunk = (ks * 4 + (l >> 4)) ^ (col & 7);
                bf[n] = *(const s16x8*)&Bs[col * 64 + chunk * 8];
            }
#pragma unroll
            for (int m = 0; m < 2; m++)
#pragma unroll
                for (int n = 0; n < 2; n++)
                    acc[m][n] = __builtin_amdgcn_mfma_f32_16x16x32_bf16(af[m], bf[n], acc[m][n], 0, 0, 0);
        }
    }
#pragma unroll
    for (int m = 0; m < 2; m++)
#pragma unroll
        for (int n = 0; n < 2; n++)
#pragma unroll
            for (int r4 = 0; r4 < 4; r4++) {
                int row = bm * 64 + wm * 32 + m * 16 + (l >> 4) * 4 + r4;
                int col = bn * 64 + wn * 32 + n * 16 + (l & 15);
                float y = acc[m][n][r4];
                float u = 1.5957691216057308f * (y + 0.044715f * y * y * y);
                float th = 1.f - 2.f / (__expf(u) + 1.f);
                g_H[row * HID + col] = f2bf(0.5f * y * (1.f + th));
            }
}

// ---------------- FFN: out = x + (H@W1^T + b1) * sigmoid(H@W2^T + b2) ----------------
__global__ __launch_bounds__(256) void ffn_gemm(const float* x, const float* b1,
                                                const float* b2, float* out) {
    __shared__ __align__(16) u16 As[64 * 64];
    __shared__ __align__(16) u16 B1s[64 * 64];
    __shared__ __align__(16) u16 B2s[64 * 64];
    int tid = threadIdx.x, l = tid & 63, w = tid >> 6;
    int wm = w >> 1, wn = w & 1;
    int bm = blockIdx.x >> 3, bn = blockIdx.x & 7;  // 32 x 8
    f32x4 acc1[2][2] = {}, acc2[2][2] = {};
    int row0 = tid >> 3, kc0 = tid & 7;
    int row1 = (256 + tid) >> 3;
    const u16* arow0 = &g_H[(bm * 64 + row0) * HID + kc0 * 8];
    const u16* arow1 = &g_H[(bm * 64 + row1) * HID + kc0 * 8];
    const u16* b1row0 = &g_W1[(bn * 64 + row0) * HID + kc0 * 8];
    const u16* b1row1 = &g_W1[(bn * 64 + row1) * HID + kc0 * 8];
    const u16* b2row0 = &g_W2[(bn * 64 + row0) * HID + kc0 * 8];
    const u16* b2row1 = &g_W2[(bn * 64 + row1) * HID + kc0 * 8];
    int sa0 = row0 * 8 + (kc0 ^ (row0 & 7));
    int sa1 = row1 * 8 + (kc0 ^ (row1 & 7));
    u32x4 ra0 = *(const u32x4*)arow0;
    u32x4 ra1 = *(const u32x4*)arow1;
    u32x4 rb10 = *(const u32x4*)b1row0;
    u32x4 rb11 = *(const u32x4*)b1row1;
    u32x4 rb20 = *(const u32x4*)b2row0;
    u32x4 rb21 = *(const u32x4*)b2row1;
    for (int kb = 0; kb < 8; kb++) {
        __syncthreads();
        ((u32x4*)As)[sa0] = ra0;
        ((u32x4*)As)[sa1] = ra1;
        ((u32x4*)B1s)[sa0] = rb10;
        ((u32x4*)B1s)[sa1] = rb11;
        ((u32x4*)B2s)[sa0] = rb20;
        ((u32x4*)B2s)[sa1] = rb21;
        if (kb < 7) {
            int k0 = (kb + 1) * 64;
            ra0 = *(const u32x4*)(arow0 + k0);
            ra1 = *(const u32x4*)(arow1 + k0);
            rb10 = *(const u32x4*)(b1row0 + k0);
            rb11 = *(const u32x4*)(b1row1 + k0);
            rb20 = *(const u32x4*)(b2row0 + k0);
            rb21 = *(const u32x4*)(b2row1 + k0);
        }
        __syncthreads();
#pragma unroll
        for (int ks = 0; ks < 2; ks++) {
            s16x8 af[2], b1f[2], b2f[2];
#pragma unroll
            for (int m = 0; m < 2; m++) {
                int row = wm * 32 + m * 16 + (l & 15);
                int chunk = (ks * 4 + (l >> 4)) ^ (row & 7);
                af[m] = *(const s16x8*)&As[row * 64 + chunk * 8];
            }
#pragma unroll
            for (int n = 0; n < 2; n++) {
                int col = wn * 32 + n * 16 + (l & 15);
                int chunk = (ks * 4 + (l >> 4)) ^ (col & 7);
                b1f[n] = *(const s16x8*)&B1s[col * 64 + chunk * 8];
                b2f[n] = *(const s16x8*)&B2s[col * 64 + chunk * 8];
            }
#pragma unroll
            for (int m = 0; m < 2; m++)
#pragma unroll
                for (int n = 0; n < 2; n++) {
                    acc1[m][n] = __builtin_amdgcn_mfma_f32_16x16x32_bf16(af[m], b1f[n], acc1[m][n], 0, 0, 0);
                    acc2[m][n] = __builtin_amdgcn_mfma_f32_16x16x32_bf16(af[m], b2f[n], acc2[m][n], 0, 0, 0);
                }
        }
    }
#pragma unroll
    for (int m = 0; m < 2; m++)
#pragma unroll
        for (int n = 0; n < 2; n++)
#pragma unroll
            for (int r4 = 0; r4 < 4; r4++) {
                int row = bm * 64 + wm * 32 + m * 16 + (l >> 4) * 4 + r4;
                int col = bn * 64 + wn * 32 + n * 16 + (l & 15);
                float g1 = acc1[m][n][r4] + b1[col];
                float g2 = acc2[m][n][r4] + b2[col];
                float sg = 1.f / (1.f + __expf(-g2));
                out[row * HID + col] = x[row * HID + col] + g1 * sg;
            }
}

extern "C" void kernel_launch(void* const* d_in, const int* in_sizes, int n_in,
                              void* d_out, int out_size, void* d_ws, size_t ws_size,
                              hipStream_t stream) {
    const float* x = (const float*)d_in[0];
    const float* lre = (const float*)d_in[1];
    const float* lim = (const float*)d_in[2];
    const float* pre = (const float*)d_in[3];
    const float* pim = (const float*)d_in[4];
    const float* bre = (const float*)d_in[5];
    const float* bim = (const float*)d_in[6];
    const float* cre = (const float*)d_in[7];
    const float* cim = (const float*)d_in[8];
    const float* lstep = (const float*)d_in[9];
    const float* w1 = (const float*)d_in[10];
    const float* b1 = (const float*)d_in[11];
    const float* w2 = (const float*)d_in[12];
    const float* b2 = (const float*)d_in[13];
    float* out = (float*)d_out;

    khat_kernel<<<8, 256, 0, stream>>>(lre, lim, pre, pim, bre, bim, cre, cim, lstep);
    k_ifft<<<512, 256, 0, stream>>>();
    fused_convert<<<2816, 256, 0, stream>>>(x, w1, w2);
    conv_gemm<<<256, 256, 0, stream>>>();
    ffn_gemm<<<256, 256, 0, stream>>>(x, b1, b2, out);
}